// Round 1
// baseline (2599.676 us; speedup 1.0000x reference)
//
#include <hip/hip_runtime.h>

#define NP1 20000
#define NP2 80000
#define KN  27

// ---------------------------------------------------------------------------
// gather kernels
// ---------------------------------------------------------------------------
__global__ __launch_bounds__(256) void gather_curr_k(
    const float* __restrict__ prior_emb, const int* __restrict__ curr_occ,
    float* __restrict__ out)
{
    int i = blockIdx.x * 256 + threadIdx.x;
    if (i >= NP1 * 64) return;
    int row = i >> 6, c = i & 63;
    out[i] = prior_emb[curr_occ[row] * 64 + c];
}

__global__ __launch_bounds__(256) void gather_next_k(
    const float* __restrict__ f, const int* __restrict__ parent_idx,
    const int* __restrict__ next_oct, const float* __restrict__ temb8,
    float* __restrict__ out)
{
    int i = blockIdx.x * 256 + threadIdx.x;
    if (i >= NP2 * 64) return;
    int row = i >> 6, c = i & 63;
    out[i] = f[parent_idx[row] * 64 + c] + temb8[next_oct[row] * 64 + c];
}

// ---------------------------------------------------------------------------
// sparse conv:  out[n] = relu( (res ? res[n] : 0) + sum_k feats[nbr[n,k]] @ W[k] )
// 128-row tile, 256 threads, thread owns 4 rows x 8 cols.
// ---------------------------------------------------------------------------
__global__ __launch_bounds__(256) void spconv_k(
    const float* __restrict__ feats, const int* __restrict__ nbr,
    const float* __restrict__ W, const float* __restrict__ res,
    float* __restrict__ out, int N)
{
    __shared__ float Ws[64 * 64];        // W[k], row-major [j][c]
    __shared__ float Gs[128 * 65];       // gathered feats, padded stride 65
    __shared__ int   idxs[128];

    const int t    = threadIdx.x;
    const int row0 = blockIdx.x * 128;
    const int tr   = t >> 3;             // 0..31
    const int tc   = t & 7;              // 0..7
    const int r0   = tr * 4;
    const int c0   = tc * 8;

    float acc[4][8] = {};

    for (int k = 0; k < KN; ++k) {
        __syncthreads();                 // previous compute done with Ws/Gs
        if (t < 128) {
            int rg  = row0 + t;
            idxs[t] = (rg < N) ? nbr[rg * KN + k] : -1;
        }
        const float* Wk = W + k * 4096;
        #pragma unroll
        for (int i = 0; i < 16; ++i) Ws[t + i * 256] = Wk[t + i * 256];
        __syncthreads();                 // idxs ready
        #pragma unroll
        for (int i = 0; i < 32; ++i) {
            int p   = t + i * 256;
            int row = p >> 6, col = p & 63;
            int idx = idxs[row];
            Gs[row * 65 + col] = (idx >= 0) ? feats[idx * 64 + col] : 0.0f;
        }
        __syncthreads();                 // tile staged

        #pragma unroll 4
        for (int j = 0; j < 64; ++j) {
            float4 w0 = *(const float4*)&Ws[j * 64 + c0];
            float4 w1 = *(const float4*)&Ws[j * 64 + c0 + 4];
            float w[8] = {w0.x, w0.y, w0.z, w0.w, w1.x, w1.y, w1.z, w1.w};
            float g[4];
            #pragma unroll
            for (int u = 0; u < 4; ++u) g[u] = Gs[(r0 + u) * 65 + j];
            #pragma unroll
            for (int u = 0; u < 4; ++u)
                #pragma unroll
                for (int v = 0; v < 8; ++v)
                    acc[u][v] += g[u] * w[v];
        }
    }

    #pragma unroll
    for (int u = 0; u < 4; ++u) {
        int rg = row0 + r0 + u;
        if (rg >= N) continue;
        #pragma unroll
        for (int v = 0; v < 8; ++v) {
            float val = acc[u][v];
            if (res) val += res[rg * 64 + c0 + v];
            val = fmaxf(val, 0.0f);
            out[rg * 64 + c0 + v] = val;
        }
    }
}

// ---------------------------------------------------------------------------
// head: per-row two MLPs + softmax(16) + bits accumulation
// one wave per row; weights staged in LDS.
// ---------------------------------------------------------------------------
__global__ __launch_bounds__(256) void head_k(
    const float* __restrict__ g, const int* __restrict__ next_occ,
    const float* __restrict__ W0a, const float* __restrict__ b0a,
    const float* __restrict__ W0b, const float* __restrict__ b0b,
    const float* __restrict__ W1a, const float* __restrict__ b1a,
    const float* __restrict__ W1b, const float* __restrict__ b1b,
    const float* __restrict__ s1_emb, const int* __restrict__ n_points,
    float* __restrict__ outp)
{
    __shared__ float sW0a[4096], sW1a[4096];
    __shared__ float sW0b[64 * 17], sW1b[64 * 17];   // padded stride 17
    __shared__ float sS1[16 * 64];
    __shared__ float sb0a[64], sb1a[64], sb0b[16], sb1b[16];

    const int t = threadIdx.x;
    for (int i = t; i < 4096; i += 256) { sW0a[i] = W0a[i]; sW1a[i] = W1a[i]; }
    for (int i = t; i < 1024; i += 256) {
        int r = i >> 4, c = i & 15;
        sW0b[r * 17 + c] = W0b[i];
        sW1b[r * 17 + c] = W1b[i];
        sS1[i] = s1_emb[i];
    }
    if (t < 64) { sb0a[t] = b0a[t]; sb1a[t] = b1a[t]; }
    if (t < 16) { sb0b[t] = b0b[t]; sb1b[t] = b1b[t]; }
    __syncthreads();

    const int lane = t & 63;
    const int wid  = (blockIdx.x << 2) + (t >> 6);
    const int nw   = gridDim.x << 2;
    float bits_acc = 0.0f;

    for (int row = wid; row < NP2; row += nw) {
        float g_c = g[row * 64 + lane];
        int occ   = next_occ[row];
        int lower = occ & 15, upper = occ >> 4;

        // ---- stage 0: lp ----
        float h = sb0a[lane];
        #pragma unroll 8
        for (int j = 0; j < 64; ++j)
            h += __shfl(g_c, j) * sW0a[j * 64 + lane];
        h = fmaxf(h, 0.0f);

        float m0 = -1e30f, s0 = 0.0f, lt0 = 0.0f;
        for (int tt = 0; tt < 16; ++tt) {
            float p = h * sW0b[lane * 17 + tt];
            #pragma unroll
            for (int s = 32; s > 0; s >>= 1) p += __shfl_xor(p, s);
            float lv = p + sb0b[tt];
            lt0 = (tt == lower) ? lv : lt0;
            float nm = fmaxf(m0, lv);
            s0 = s0 * __expf(m0 - nm) + __expf(lv - nm);
            m0 = nm;
        }
        float p0 = __expf(lt0 - m0) / s0;
        float b0v = fminf(fmaxf(-log2f(p0 + 1e-10f), 0.0f), 50.0f);

        // ---- stage 1: up ----
        float h1in = g_c + sS1[lower * 64 + lane];
        float h1 = sb1a[lane];
        #pragma unroll 8
        for (int j = 0; j < 64; ++j)
            h1 += __shfl(h1in, j) * sW1a[j * 64 + lane];
        h1 = fmaxf(h1, 0.0f);

        float m1 = -1e30f, s1 = 0.0f, lt1 = 0.0f;
        for (int tt = 0; tt < 16; ++tt) {
            float p = h1 * sW1b[lane * 17 + tt];
            #pragma unroll
            for (int s = 32; s > 0; s >>= 1) p += __shfl_xor(p, s);
            float lv = p + sb1b[tt];
            lt1 = (tt == upper) ? lv : lt1;
            float nm = fmaxf(m1, lv);
            s1 = s1 * __expf(m1 - nm) + __expf(lv - nm);
            m1 = nm;
        }
        float p1 = __expf(lt1 - m1) / s1;
        float b1v = fminf(fmaxf(-log2f(p1 + 1e-10f), 0.0f), 50.0f);

        bits_acc += b0v + b1v;
    }

    if (lane == 0)
        atomicAdd(outp, bits_acc / (float)(*n_points));
}

// ---------------------------------------------------------------------------
extern "C" void kernel_launch(void* const* d_in, const int* in_sizes, int n_in,
                              void* d_out, int out_size, void* d_ws, size_t ws_size,
                              hipStream_t stream)
{
    const float* prior_emb = (const float*)d_in[0];
    const float* temb8     = (const float*)d_in[1];
    const float* Wp        = (const float*)d_in[2];
    const float* Wt        = (const float*)d_in[3];
    const float* W0a       = (const float*)d_in[4];
    const float* b0a       = (const float*)d_in[5];
    const float* W0b       = (const float*)d_in[6];
    const float* b0b       = (const float*)d_in[7];
    const float* W1a       = (const float*)d_in[8];
    const float* b1a       = (const float*)d_in[9];
    const float* W1b       = (const float*)d_in[10];
    const float* b1b       = (const float*)d_in[11];
    const float* s1_emb    = (const float*)d_in[12];
    const int*   curr_occ  = (const int*)d_in[13];
    const int*   next_occ  = (const int*)d_in[14];
    const int*   next_oct  = (const int*)d_in[15];
    const int*   parent    = (const int*)d_in[16];
    const int*   nbr_curr  = (const int*)d_in[17];
    const int*   nbr_next  = (const int*)d_in[18];
    const int*   n_points  = (const int*)d_in[19];
    float* out = (float*)d_out;

    float* fA = (float*)d_ws;
    float* fB = fA + NP1 * 64;
    float* fC = fB + NP1 * 64;
    float* gA = fC + NP1 * 64;
    float* gB = gA + NP2 * 64;
    float* gC = gB + NP2 * 64;

    const size_t WL = (size_t)KN * 64 * 64;

    hipMemsetAsync(d_out, 0, sizeof(float), stream);

    gather_curr_k<<<(NP1 * 64 + 255) / 256, 256, 0, stream>>>(prior_emb, curr_occ, fA);

    // current level: conv0 + 2 resnets
    spconv_k<<<(NP1 + 127) / 128, 256, 0, stream>>>(fA, nbr_curr, Wp + 0 * WL, nullptr, fB, NP1);
    spconv_k<<<(NP1 + 127) / 128, 256, 0, stream>>>(fB, nbr_curr, Wp + 1 * WL, nullptr, fA, NP1);
    spconv_k<<<(NP1 + 127) / 128, 256, 0, stream>>>(fA, nbr_curr, Wp + 2 * WL, fB,      fC, NP1);
    spconv_k<<<(NP1 + 127) / 128, 256, 0, stream>>>(fC, nbr_curr, Wp + 3 * WL, nullptr, fA, NP1);
    spconv_k<<<(NP1 + 127) / 128, 256, 0, stream>>>(fA, nbr_curr, Wp + 4 * WL, fC,      fB, NP1);

    gather_next_k<<<(NP2 * 64 + 255) / 256, 256, 0, stream>>>(fB, parent, next_oct, temb8, gA);

    // next level: conv0 + 2 resnets
    spconv_k<<<(NP2 + 127) / 128, 256, 0, stream>>>(gA, nbr_next, Wt + 0 * WL, nullptr, gB, NP2);
    spconv_k<<<(NP2 + 127) / 128, 256, 0, stream>>>(gB, nbr_next, Wt + 1 * WL, nullptr, gA, NP2);
    spconv_k<<<(NP2 + 127) / 128, 256, 0, stream>>>(gA, nbr_next, Wt + 2 * WL, gB,      gC, NP2);
    spconv_k<<<(NP2 + 127) / 128, 256, 0, stream>>>(gC, nbr_next, Wt + 3 * WL, nullptr, gA, NP2);
    spconv_k<<<(NP2 + 127) / 128, 256, 0, stream>>>(gA, nbr_next, Wt + 4 * WL, gC,      gB, NP2);

    head_k<<<256, 256, 0, stream>>>(gB, next_occ,
                                    W0a, b0a, W0b, b0b, W1a, b1a, W1b, b1b,
                                    s1_emb, n_points, out);
}

// Round 2
// 517.850 us; speedup vs baseline: 5.0201x; 5.0201x over previous
//
#include <hip/hip_runtime.h>

#define NP1 20000
#define NP2 80000
#define KN  27

typedef unsigned short ushort;
typedef unsigned int   uint;
typedef __attribute__((ext_vector_type(8))) short short8v;
typedef __attribute__((ext_vector_type(4))) float f32x4;

__device__ __forceinline__ ushort f2bf(float x) {
    union { float f; uint u; } v; v.f = x;
    uint r = v.u + 0x7fffu + ((v.u >> 16) & 1u);
    return (ushort)(r >> 16);
}
__device__ __forceinline__ float bf2f(ushort s) {
    union { uint u; float f; } v; v.u = ((uint)s) << 16;
    return v.f;
}
__device__ __forceinline__ void gload_lds16(const void* g, void* l) {
    __builtin_amdgcn_global_load_lds(
        (const __attribute__((address_space(1))) unsigned int*)g,
        (__attribute__((address_space(3))) unsigned int*)l, 16, 0, 0);
}

// ---------------------------------------------------------------------------
// prep: transpose 64x64 (j,c)->(c,j) taps to bf16 with chunk swizzle
// dst[k][c][jj] = W[k][ j=((jj>>3)^(c&7))*8+(jj&7) ][c]
// ---------------------------------------------------------------------------
__global__ __launch_bounds__(256) void prep_wT_k(const float* __restrict__ W,
                                                 ushort* __restrict__ dst, int ntaps)
{
    int i = blockIdx.x * 256 + threadIdx.x;
    if (i >= ntaps * 4096) return;
    int k = i >> 12, rem = i & 4095, c = rem >> 6, jj = rem & 63;
    int j = (((jj >> 3) ^ (c & 7)) << 3) | (jj & 7);
    dst[i] = f2bf(W[(size_t)k * 4096 + j * 64 + c]);
}
// W0b/W1b: [64][16] -> [16][64] swizzled
__global__ __launch_bounds__(256) void prep_wbT_k(const float* __restrict__ W,
                                                  ushort* __restrict__ dst)
{
    int i = blockIdx.x * 256 + threadIdx.x;
    if (i >= 1024) return;
    int c = i >> 6, jj = i & 63;
    int j = (((jj >> 3) ^ (c & 7)) << 3) | (jj & 7);
    dst[i] = f2bf(W[j * 16 + c]);
}
// s1_emb [16][64] -> bf16, row-swizzled
__global__ __launch_bounds__(256) void prep_s1_k(const float* __restrict__ s,
                                                 ushort* __restrict__ dst)
{
    int i = blockIdx.x * 256 + threadIdx.x;
    if (i >= 1024) return;
    int e = i >> 6, jj = i & 63;
    int j = (((jj >> 3) ^ (e & 7)) << 3) | (jj & 7);
    dst[i] = f2bf(s[e * 64 + j]);
}

// ---------------------------------------------------------------------------
// gathers (produce bf16 feature buffers, plain row-major)
// ---------------------------------------------------------------------------
__global__ __launch_bounds__(256) void gather_curr_k(
    const float* __restrict__ prior_emb, const int* __restrict__ curr_occ,
    ushort* __restrict__ out)
{
    int i = blockIdx.x * 256 + threadIdx.x;
    if (i >= NP1 * 32) return;
    int row = i >> 5, cp = (i & 31) * 2;
    const float* src = prior_emb + (size_t)curr_occ[row] * 64 + cp;
    uint pk = (uint)f2bf(src[0]) | ((uint)f2bf(src[1]) << 16);
    *(uint*)((char*)out + (size_t)row * 128 + cp * 2) = pk;
}

__global__ __launch_bounds__(256) void gather_next_k(
    const ushort* __restrict__ f, const int* __restrict__ parent_idx,
    const int* __restrict__ next_oct, const float* __restrict__ temb8,
    ushort* __restrict__ out)
{
    int i = blockIdx.x * 256 + threadIdx.x;
    if (i >= NP2 * 32) return;
    int row = i >> 5, cp = (i & 31) * 2;
    const ushort* fs = f + (size_t)parent_idx[row] * 64 + cp;
    const float* ts = temb8 + (size_t)next_oct[row] * 64 + cp;
    float v0 = bf2f(fs[0]) + ts[0];
    float v1 = bf2f(fs[1]) + ts[1];
    uint pk = (uint)f2bf(v0) | ((uint)f2bf(v1) << 16);
    *(uint*)((char*)out + (size_t)row * 128 + cp * 2) = pk;
}

// ---------------------------------------------------------------------------
// MFMA sparse conv: out = relu((res?:0) + sum_k gather_k(feats) @ W[k])
// block: 128 rows x 64 cols, 4 waves, wave = 32 rows (2 m-blocks x 4 n-blocks)
// ---------------------------------------------------------------------------
__global__ __launch_bounds__(256) void spconv_mfma_k(
    const ushort* __restrict__ feats, const int* __restrict__ nbr,
    const ushort* __restrict__ Wsw, const ushort* __restrict__ res,
    ushort* __restrict__ out, int N, const ushort* __restrict__ zpage)
{
    __shared__ __align__(16) char sm[16384 + 8192];
    char* sG = sm;
    char* sW = sm + 16384;
    const int t = threadIdx.x;
    const int w = t >> 6, l = t & 63;
    const int row0 = blockIdx.x * 128;
    const int lr = l & 15, lhi = l >> 4;

    f32x4 acc[2][4];
    #pragma unroll
    for (int a = 0; a < 2; ++a)
        #pragma unroll
        for (int b = 0; b < 4; ++b) acc[a][b] = (f32x4)0.0f;

    for (int k = 0; k < KN; ++k) {
        __syncthreads();
        // stage W tap (8 KB, pre-swizzled, linear copy)
        const char* wsrc = (const char*)Wsw + (size_t)k * 8192;
        #pragma unroll
        for (int i = 0; i < 2; ++i) {
            int off = (w * 2 + i) * 1024;
            gload_lds16(wsrc + off + l * 16, sW + off);
        }
        // stage G tile (16 KB) via gathered, source-swizzled loads
        #pragma unroll
        for (int i = 0; i < 4; ++i) {
            int rt = w * 32 + i * 8 + (l >> 3);
            int rg = row0 + rt;
            int idx = (rg < N) ? nbr[(size_t)rg * KN + k] : -1;
            const char* src = (idx >= 0)
                ? (const char*)feats + (size_t)idx * 128 + (((l & 7) ^ (rt & 7)) << 4)
                : (const char*)zpage + ((l & 7) << 4);
            gload_lds16(src, sG + (w * 32 + i * 8) * 128);
        }
        __syncthreads();

        #pragma unroll
        for (int j0 = 0; j0 < 2; ++j0) {
            short8v a[2], b[4];
            #pragma unroll
            for (int mb = 0; mb < 2; ++mb) {
                int r = w * 32 + mb * 16 + lr;
                int ch = (j0 * 4 + lhi) ^ (r & 7);
                a[mb] = *(const short8v*)(sG + r * 128 + ch * 16);
            }
            #pragma unroll
            for (int nb = 0; nb < 4; ++nb) {
                int c = nb * 16 + lr;
                int ch = (j0 * 4 + lhi) ^ (c & 7);
                b[nb] = *(const short8v*)(sW + c * 128 + ch * 16);
            }
            #pragma unroll
            for (int mb = 0; mb < 2; ++mb)
                #pragma unroll
                for (int nb = 0; nb < 4; ++nb)
                    acc[mb][nb] = __builtin_amdgcn_mfma_f32_16x16x32_bf16(
                        a[mb], b[nb], acc[mb][nb], 0, 0, 0);
        }
    }

    // epilogue: +res, relu, pack 2 cols, store bf16
    #pragma unroll
    for (int mb = 0; mb < 2; ++mb) {
        #pragma unroll
        for (int nb = 0; nb < 4; ++nb) {
            #pragma unroll
            for (int r = 0; r < 4; ++r) {
                int rg = row0 + w * 32 + mb * 16 + lhi * 4 + r;
                int c = nb * 16 + lr;
                float v = acc[mb][nb][r];
                if (res != nullptr && rg < N) v += bf2f(res[(size_t)rg * 64 + c]);
                v = fmaxf(v, 0.0f);
                float o = __shfl_xor(v, 1);
                if (!(l & 1) && rg < N) {
                    uint pk = (uint)f2bf(v) | ((uint)f2bf(o) << 16);
                    *(uint*)((char*)out + (size_t)rg * 128 + (c << 1)) = pk;
                }
            }
        }
    }
}

// ---------------------------------------------------------------------------
// MFMA head: per 128-row block, two MLP stages + softmax(16) + bits
// LDS: sG 16K | sH 16K | [W0aT W1aT W0bT W1bT s1b] 22528B | biases 640B
// ---------------------------------------------------------------------------
__global__ __launch_bounds__(256) void head_mfma_k(
    const ushort* __restrict__ G, const int* __restrict__ next_occ,
    const ushort* __restrict__ Wsmall,
    const float* __restrict__ b0a, const float* __restrict__ b1a,
    const float* __restrict__ b0b, const float* __restrict__ b1b,
    const int* __restrict__ n_points, float* __restrict__ outp)
{
    __shared__ __align__(16) char sm[32768 + 22528 + 640];
    char* sG = sm;
    char* sH = sm + 16384;
    char* sWs = sm + 32768;
    float* sBf = (float*)(sm + 32768 + 22528);

    const int t = threadIdx.x;
    const int w = t >> 6, l = t & 63;
    const int row0 = blockIdx.x * 128;
    const int lr = l & 15, lhi = l >> 4;

    // stage G (source-swizzled)
    #pragma unroll
    for (int i = 0; i < 4; ++i) {
        int rt = w * 32 + i * 8 + (l >> 3);
        int row = row0 + rt;
        gload_lds16((const char*)G + (size_t)row * 128 + (((l & 7) ^ (rt & 7)) << 4),
                    sG + (w * 32 + i * 8) * 128);
    }
    // stage weights (22 KB linear)
    for (int i = w; i < 22; i += 4)
        gload_lds16((const char*)Wsmall + i * 1024 + l * 16, sWs + i * 1024);
    // biases
    if (t < 64)                 sBf[t] = b0a[t];
    else if (t < 128)           sBf[t] = b1a[t - 64];
    else if (t < 144)           sBf[t] = b0b[t - 128 + 128 - 128] , sBf[128 + (t - 128)] = b0b[t - 128];
    else if (t < 160)           sBf[144 + (t - 144)] = b1b[t - 144];
    __syncthreads();

    const int wr0 = w * 32;
    float bacc = 0.0f;

    // ======== stage 0 ========
    f32x4 acc[2][4];
    #pragma unroll
    for (int a = 0; a < 2; ++a)
        #pragma unroll
        for (int b = 0; b < 4; ++b) acc[a][b] = (f32x4)0.0f;
    #pragma unroll
    for (int j0 = 0; j0 < 2; ++j0) {
        short8v a[2], b[4];
        #pragma unroll
        for (int mb = 0; mb < 2; ++mb) {
            int r = wr0 + mb * 16 + lr;
            int ch = (j0 * 4 + lhi) ^ (r & 7);
            a[mb] = *(const short8v*)(sG + r * 128 + ch * 16);
        }
        #pragma unroll
        for (int nb = 0; nb < 4; ++nb) {
            int c = nb * 16 + lr;
            int ch = (j0 * 4 + lhi) ^ (c & 7);
            b[nb] = *(const short8v*)(sWs + c * 128 + ch * 16);   // W0aT
        }
        #pragma unroll
        for (int mb = 0; mb < 2; ++mb)
            #pragma unroll
            for (int nb = 0; nb < 4; ++nb)
                acc[mb][nb] = __builtin_amdgcn_mfma_f32_16x16x32_bf16(
                    a[mb], b[nb], acc[mb][nb], 0, 0, 0);
    }
    // H0 = relu(acc + b0a) -> sH (bf16, swizzled)
    #pragma unroll
    for (int mb = 0; mb < 2; ++mb)
        #pragma unroll
        for (int nb = 0; nb < 4; ++nb) {
            float bias = sBf[nb * 16 + lr];
            #pragma unroll
            for (int r = 0; r < 4; ++r) {
                int row = wr0 + mb * 16 + lhi * 4 + r;
                int j = nb * 16 + lr;
                float v = fmaxf(acc[mb][nb][r] + bias, 0.0f);
                *(ushort*)(sH + row * 128 + (((j >> 3) ^ (row & 7)) << 4) + (j & 7) * 2) = f2bf(v);
            }
        }
    // logits0 = H0 @ W0bT
    f32x4 lg[2];
    lg[0] = (f32x4)0.0f; lg[1] = (f32x4)0.0f;
    #pragma unroll
    for (int j0 = 0; j0 < 2; ++j0) {
        short8v a[2], b;
        #pragma unroll
        for (int mb = 0; mb < 2; ++mb) {
            int r = wr0 + mb * 16 + lr;
            int ch = (j0 * 4 + lhi) ^ (r & 7);
            a[mb] = *(const short8v*)(sH + r * 128 + ch * 16);
        }
        {
            int c = lr;
            int ch = (j0 * 4 + lhi) ^ (c & 7);
            b = *(const short8v*)(sWs + 16384 + c * 128 + ch * 16); // W0bT
        }
        #pragma unroll
        for (int mb = 0; mb < 2; ++mb)
            lg[mb] = __builtin_amdgcn_mfma_f32_16x16x32_bf16(a[mb], b, lg[mb], 0, 0, 0);
    }
    #pragma unroll
    for (int mb = 0; mb < 2; ++mb)
        #pragma unroll
        for (int r = 0; r < 4; ++r) {
            int row = row0 + wr0 + mb * 16 + lhi * 4 + r;
            int lower = next_occ[row] & 15;
            float lv = lg[mb][r] + sBf[128 + lr];
            float m = lv;
            #pragma unroll
            for (int s = 1; s < 16; s <<= 1) m = fmaxf(m, __shfl_xor(m, s));
            float e = __expf(lv - m), ss = e;
            #pragma unroll
            for (int s = 1; s < 16; s <<= 1) ss += __shfl_xor(ss, s);
            float lt = __shfl(lv, (l & 48) + lower);
            float p = __expf(lt - m) / ss;
            float bits = fminf(fmaxf(-log2f(p + 1e-10f), 0.0f), 50.0f);
            if (lr == 0) bacc += bits;
        }

    // ======== stage 1 ========
    f32x4 acc1[2][4];
    #pragma unroll
    for (int a = 0; a < 2; ++a)
        #pragma unroll
        for (int b = 0; b < 4; ++b) acc1[a][b] = (f32x4)0.0f;
    #pragma unroll
    for (int j0 = 0; j0 < 2; ++j0) {
        short8v a[2], b[4];
        #pragma unroll
        for (int mb = 0; mb < 2; ++mb) {
            int rloc = wr0 + mb * 16 + lr;
            int low = next_occ[row0 + rloc] & 15;
            int ch = (j0 * 4 + lhi) ^ (rloc & 7);
            short8v g8 = *(const short8v*)(sG + rloc * 128 + ch * 16);
            int che = (j0 * 4 + lhi) ^ (low & 7);
            short8v e8 = *(const short8v*)(sWs + 20480 + low * 128 + che * 16); // s1b
            #pragma unroll
            for (int e = 0; e < 8; ++e) {
                float f = bf2f((ushort)g8[e]) + bf2f((ushort)e8[e]);
                a[mb][e] = (short)f2bf(f);
            }
        }
        #pragma unroll
        for (int nb = 0; nb < 4; ++nb) {
            int c = nb * 16 + lr;
            int ch = (j0 * 4 + lhi) ^ (c & 7);
            b[nb] = *(const short8v*)(sWs + 8192 + c * 128 + ch * 16);  // W1aT
        }
        #pragma unroll
        for (int mb = 0; mb < 2; ++mb)
            #pragma unroll
            for (int nb = 0; nb < 4; ++nb)
                acc1[mb][nb] = __builtin_amdgcn_mfma_f32_16x16x32_bf16(
                    a[mb], b[nb], acc1[mb][nb], 0, 0, 0);
    }
    // H1 = relu(acc1 + b1a) -> sH
    #pragma unroll
    for (int mb = 0; mb < 2; ++mb)
        #pragma unroll
        for (int nb = 0; nb < 4; ++nb) {
            float bias = sBf[64 + nb * 16 + lr];
            #pragma unroll
            for (int r = 0; r < 4; ++r) {
                int row = wr0 + mb * 16 + lhi * 4 + r;
                int j = nb * 16 + lr;
                float v = fmaxf(acc1[mb][nb][r] + bias, 0.0f);
                *(ushort*)(sH + row * 128 + (((j >> 3) ^ (row & 7)) << 4) + (j & 7) * 2) = f2bf(v);
            }
        }
    // logits1 = H1 @ W1bT
    lg[0] = (f32x4)0.0f; lg[1] = (f32x4)0.0f;
    #pragma unroll
    for (int j0 = 0; j0 < 2; ++j0) {
        short8v a[2], b;
        #pragma unroll
        for (int mb = 0; mb < 2; ++mb) {
            int r = wr0 + mb * 16 + lr;
            int ch = (j0 * 4 + lhi) ^ (r & 7);
            a[mb] = *(const short8v*)(sH + r * 128 + ch * 16);
        }
        {
            int c = lr;
            int ch = (j0 * 4 + lhi) ^ (c & 7);
            b = *(const short8v*)(sWs + 18432 + c * 128 + ch * 16); // W1bT
        }
        #pragma unroll
        for (int mb = 0; mb < 2; ++mb)
            lg[mb] = __builtin_amdgcn_mfma_f32_16x16x32_bf16(a[mb], b, lg[mb], 0, 0, 0);
    }
    #pragma unroll
    for (int mb = 0; mb < 2; ++mb)
        #pragma unroll
        for (int r = 0; r < 4; ++r) {
            int row = row0 + wr0 + mb * 16 + lhi * 4 + r;
            int upper = next_occ[row] >> 4;
            float lv = lg[mb][r] + sBf[144 + lr];
            float m = lv;
            #pragma unroll
            for (int s = 1; s < 16; s <<= 1) m = fmaxf(m, __shfl_xor(m, s));
            float e = __expf(lv - m), ss = e;
            #pragma unroll
            for (int s = 1; s < 16; s <<= 1) ss += __shfl_xor(ss, s);
            float lt = __shfl(lv, (l & 48) + upper);
            float p = __expf(lt - m) / ss;
            float bits = fminf(fmaxf(-log2f(p + 1e-10f), 0.0f), 50.0f);
            if (lr == 0) bacc += bits;
        }

    bacc += __shfl_xor(bacc, 16);
    bacc += __shfl_xor(bacc, 32);
    if (l == 0) atomicAdd(outp, bacc / (float)(*n_points));
}

// ---------------------------------------------------------------------------
extern "C" void kernel_launch(void* const* d_in, const int* in_sizes, int n_in,
                              void* d_out, int out_size, void* d_ws, size_t ws_size,
                              hipStream_t stream)
{
    const float* prior_emb = (const float*)d_in[0];
    const float* temb8     = (const float*)d_in[1];
    const float* Wp        = (const float*)d_in[2];
    const float* Wt        = (const float*)d_in[3];
    const float* W0a       = (const float*)d_in[4];
    const float* b0a       = (const float*)d_in[5];
    const float* W0b       = (const float*)d_in[6];
    const float* b0b       = (const float*)d_in[7];
    const float* W1a       = (const float*)d_in[8];
    const float* b1a       = (const float*)d_in[9];
    const float* W1b       = (const float*)d_in[10];
    const float* b1b       = (const float*)d_in[11];
    const float* s1_emb    = (const float*)d_in[12];
    const int*   curr_occ  = (const int*)d_in[13];
    const int*   next_occ  = (const int*)d_in[14];
    const int*   next_oct  = (const int*)d_in[15];
    const int*   parent    = (const int*)d_in[16];
    const int*   nbr_curr  = (const int*)d_in[17];
    const int*   nbr_next  = (const int*)d_in[18];
    const int*   n_points  = (const int*)d_in[19];
    float* out = (float*)d_out;

    // ws layout (bytes, 256-aligned)
    char* wsb = (char*)d_ws;
    ushort* zpage = (ushort*)wsb;                       // 256 B
    size_t off = 256;
    ushort* WpT = (ushort*)(wsb + off); off += (size_t)135 * 4096 * 2;   // 1105920
    ushort* WtT = (ushort*)(wsb + off); off += (size_t)135 * 4096 * 2;
    ushort* Wsmall = (ushort*)(wsb + off);              // W0aT W1aT W0bT W1bT s1b
    ushort* W0aT = Wsmall;
    ushort* W1aT = Wsmall + 4096;
    ushort* W0bT = Wsmall + 8192;
    ushort* W1bT = Wsmall + 9216;
    ushort* s1bT = Wsmall + 10240;
    off += 11264 * 2;                                   // 22528
    off = (off + 255) & ~(size_t)255;
    ushort* fA = (ushort*)(wsb + off); off += (size_t)NP1 * 64 * 2;
    ushort* fB = (ushort*)(wsb + off); off += (size_t)NP1 * 64 * 2;
    ushort* fC = (ushort*)(wsb + off); off += (size_t)NP1 * 64 * 2;
    ushort* gA = (ushort*)(wsb + off); off += (size_t)NP2 * 64 * 2;
    ushort* gB = (ushort*)(wsb + off); off += (size_t)NP2 * 64 * 2;
    ushort* gC = (ushort*)(wsb + off); off += (size_t)NP2 * 64 * 2;

    hipMemsetAsync(d_out, 0, sizeof(float), stream);
    hipMemsetAsync(zpage, 0, 256, stream);

    prep_wT_k<<<(135 * 4096 + 255) / 256, 256, 0, stream>>>(Wp, WpT, 135);
    prep_wT_k<<<(135 * 4096 + 255) / 256, 256, 0, stream>>>(Wt, WtT, 135);
    prep_wT_k<<<16, 256, 0, stream>>>(W0a, W0aT, 1);
    prep_wT_k<<<16, 256, 0, stream>>>(W1a, W1aT, 1);
    prep_wbT_k<<<4, 256, 0, stream>>>(W0b, W0bT);
    prep_wbT_k<<<4, 256, 0, stream>>>(W1b, W1bT);
    prep_s1_k<<<4, 256, 0, stream>>>(s1_emb, s1bT);

    gather_curr_k<<<(NP1 * 32 + 255) / 256, 256, 0, stream>>>(prior_emb, curr_occ, fA);

    const size_t WT = (size_t)KN * 4096;  // ushorts per conv
    int g1 = (NP1 + 127) / 128, g2 = (NP2 + 127) / 128;

    spconv_mfma_k<<<g1, 256, 0, stream>>>(fA, nbr_curr, WpT + 0 * WT, nullptr, fB, NP1, zpage);
    spconv_mfma_k<<<g1, 256, 0, stream>>>(fB, nbr_curr, WpT + 1 * WT, nullptr, fC, NP1, zpage);
    spconv_mfma_k<<<g1, 256, 0, stream>>>(fC, nbr_curr, WpT + 2 * WT, fB,      fA, NP1, zpage);
    spconv_mfma_k<<<g1, 256, 0, stream>>>(fA, nbr_curr, WpT + 3 * WT, nullptr, fC, NP1, zpage);
    spconv_mfma_k<<<g1, 256, 0, stream>>>(fC, nbr_curr, WpT + 4 * WT, fA,      fB, NP1, zpage);

    gather_next_k<<<(NP2 * 32 + 255) / 256, 256, 0, stream>>>(fB, parent, next_oct, temb8, gA);

    spconv_mfma_k<<<g2, 256, 0, stream>>>(gA, nbr_next, WtT + 0 * WT, nullptr, gB, NP2, zpage);
    spconv_mfma_k<<<g2, 256, 0, stream>>>(gB, nbr_next, WtT + 1 * WT, nullptr, gC, NP2, zpage);
    spconv_mfma_k<<<g2, 256, 0, stream>>>(gC, nbr_next, WtT + 2 * WT, gB,      gA, NP2, zpage);
    spconv_mfma_k<<<g2, 256, 0, stream>>>(gA, nbr_next, WtT + 3 * WT, nullptr, gC, NP2, zpage);
    spconv_mfma_k<<<g2, 256, 0, stream>>>(gC, nbr_next, WtT + 4 * WT, gA,      gB, NP2, zpage);

    head_mfma_k<<<g2, 256, 0, stream>>>(gB, next_occ, Wsmall,
                                        b0a, b1a, b0b, b1b, n_points, out);
}

// Round 3
// 320.760 us; speedup vs baseline: 8.1047x; 1.6144x over previous
//
#include <hip/hip_runtime.h>

#define NP1 20000
#define NP2 80000
#define KN  27

typedef unsigned short ushort;
typedef unsigned int   uint;
typedef __attribute__((ext_vector_type(8))) short short8v;
typedef __attribute__((ext_vector_type(4))) float f32x4;

__device__ __forceinline__ ushort f2bf(float x) {
    union { float f; uint u; } v; v.f = x;
    uint r = v.u + 0x7fffu + ((v.u >> 16) & 1u);
    return (ushort)(r >> 16);
}
__device__ __forceinline__ float bf2f(ushort s) {
    union { uint u; float f; } v; v.u = ((uint)s) << 16;
    return v.f;
}
__device__ __forceinline__ void gload_lds16(const void* g, void* l) {
    __builtin_amdgcn_global_load_lds(
        (const __attribute__((address_space(1))) unsigned int*)g,
        (__attribute__((address_space(3))) unsigned int*)l, 16, 0, 0);
}

// ---------------------------------------------------------------------------
// prep: transpose 64x64 (j,c)->(c,j) taps to bf16 with chunk swizzle
// dst[k][c][jj] = W[k][ j=((jj>>3)^(c&7))*8+(jj&7) ][c]
// ---------------------------------------------------------------------------
__global__ __launch_bounds__(256) void prep_wT_k(const float* __restrict__ W,
                                                 ushort* __restrict__ dst, int ntaps)
{
    int i = blockIdx.x * 256 + threadIdx.x;
    if (i >= ntaps * 4096) return;
    int k = i >> 12, rem = i & 4095, c = rem >> 6, jj = rem & 63;
    int j = (((jj >> 3) ^ (c & 7)) << 3) | (jj & 7);
    dst[i] = f2bf(W[(size_t)k * 4096 + j * 64 + c]);
}
__global__ __launch_bounds__(256) void prep_wbT_k(const float* __restrict__ W,
                                                  ushort* __restrict__ dst)
{
    int i = blockIdx.x * 256 + threadIdx.x;
    if (i >= 1024) return;
    int c = i >> 6, jj = i & 63;
    int j = (((jj >> 3) ^ (c & 7)) << 3) | (jj & 7);
    dst[i] = f2bf(W[j * 16 + c]);
}
__global__ __launch_bounds__(256) void prep_s1_k(const float* __restrict__ s,
                                                 ushort* __restrict__ dst)
{
    int i = blockIdx.x * 256 + threadIdx.x;
    if (i >= 1024) return;
    int e = i >> 6, jj = i & 63;
    int j = (((jj >> 3) ^ (e & 7)) << 3) | (jj & 7);
    dst[i] = f2bf(s[e * 64 + j]);
}

// ---------------------------------------------------------------------------
// gathers (produce bf16 feature buffers, plain row-major)
// ---------------------------------------------------------------------------
__global__ __launch_bounds__(256) void gather_curr_k(
    const float* __restrict__ prior_emb, const int* __restrict__ curr_occ,
    ushort* __restrict__ out)
{
    int i = blockIdx.x * 256 + threadIdx.x;
    if (i >= NP1 * 32) return;
    int row = i >> 5, cp = (i & 31) * 2;
    const float* src = prior_emb + (size_t)curr_occ[row] * 64 + cp;
    uint pk = (uint)f2bf(src[0]) | ((uint)f2bf(src[1]) << 16);
    *(uint*)((char*)out + (size_t)row * 128 + cp * 2) = pk;
}

__global__ __launch_bounds__(256) void gather_next_k(
    const ushort* __restrict__ f, const int* __restrict__ parent_idx,
    const int* __restrict__ next_oct, const float* __restrict__ temb8,
    ushort* __restrict__ out)
{
    int i = blockIdx.x * 256 + threadIdx.x;
    if (i >= NP2 * 32) return;
    int row = i >> 5, cp = (i & 31) * 2;
    const ushort* fs = f + (size_t)parent_idx[row] * 64 + cp;
    const float* ts = temb8 + (size_t)next_oct[row] * 64 + cp;
    float v0 = bf2f(fs[0]) + ts[0];
    float v1 = bf2f(fs[1]) + ts[1];
    uint pk = (uint)f2bf(v0) | ((uint)f2bf(v1) << 16);
    *(uint*)((char*)out + (size_t)row * 128 + cp * 2) = pk;
}

// ---------------------------------------------------------------------------
// Pipelined MFMA sparse conv.
// Block = NW waves, each wave owns MB*16 rows x 64 cols. ROWS = NW*MB*16.
// Double-buffered LDS {G tile | W tap}; ONE __syncthreads per tap:
//   iter k: sync (drains my stage(k) vmcnt + rendezvous) ->
//           issue stage(k+1) into other buffer -> prefetch idx(k+2) regs ->
//           MFMA on buf[k&1].
// Grid sized so N % ROWS == 0 (no tail guards).
// ---------------------------------------------------------------------------
template<int NW, int MB>
__global__ __launch_bounds__(NW * 64) void spconv_pipe_k(
    const ushort* __restrict__ feats, const int* __restrict__ nbr,
    const ushort* __restrict__ Wsw, const ushort* __restrict__ res,
    ushort* __restrict__ out, const ushort* __restrict__ zpage)
{
    constexpr int ROWS   = NW * MB * 16;
    constexpr int RPW    = MB * 16;
    constexpr int GB     = ROWS * 128;          // G tile bytes
    constexpr int BUFB   = GB + 8192;           // G + W per buffer
    constexpr int GLOADS = GB / (NW * 64 * 16);
    constexpr int WLOADS = 8192 / (NW * 64 * 16);

    __shared__ __align__(16) char sm[2 * BUFB];

    const int t = threadIdx.x;
    const int w = t >> 6, l = t & 63;
    const int row0 = blockIdx.x * ROWS;
    const int lr = l & 15, lhi = l >> 4;
    const int chbase = lr & 7;
    const int srcswz = (((l & 7) ^ (l >> 3)) << 4);

    const int* nbp[GLOADS];
    #pragma unroll
    for (int i = 0; i < GLOADS; ++i) {
        int rt = w * RPW + i * 8 + (l >> 3);
        nbp[i] = nbr + (size_t)(row0 + rt) * KN;
    }

    f32x4 acc[MB][4];
    #pragma unroll
    for (int a = 0; a < MB; ++a)
        #pragma unroll
        for (int b = 0; b < 4; ++b) acc[a][b] = (f32x4)0.0f;

    int idxn[GLOADS];

    // ---- prologue: stage tap 0, prefetch idx(1) ----
    {
        int idx0[GLOADS];
        #pragma unroll
        for (int i = 0; i < GLOADS; ++i) idx0[i] = nbp[i][0];
        const char* wsrc = (const char*)Wsw;
        #pragma unroll
        for (int i = 0; i < WLOADS; ++i) {
            int off = (w * WLOADS + i) * 1024;
            gload_lds16(wsrc + off + l * 16, sm + GB + off);
        }
        #pragma unroll
        for (int i = 0; i < GLOADS; ++i) {
            const char* src = (idx0[i] >= 0)
                ? (const char*)feats + (size_t)idx0[i] * 128 + srcswz
                : (const char*)zpage + srcswz;
            gload_lds16(src, sm + (w * RPW + i * 8) * 128);
        }
        #pragma unroll
        for (int i = 0; i < GLOADS; ++i) idxn[i] = nbp[i][1];
    }

    for (int k = 0; k < KN; ++k) {
        char* cur = sm + (k & 1) * BUFB;
        char* nxt = sm + ((k + 1) & 1) * BUFB;

        __syncthreads();   // vmcnt(0): my stage(k)+idx(k+1) done; all waves synced

        if (k < KN - 1) {
            const char* wsrc = (const char*)Wsw + (size_t)(k + 1) * 8192;
            #pragma unroll
            for (int i = 0; i < WLOADS; ++i) {
                int off = (w * WLOADS + i) * 1024;
                gload_lds16(wsrc + off + l * 16, nxt + GB + off);
            }
            #pragma unroll
            for (int i = 0; i < GLOADS; ++i) {
                const char* src = (idxn[i] >= 0)
                    ? (const char*)feats + (size_t)idxn[i] * 128 + srcswz
                    : (const char*)zpage + srcswz;
                gload_lds16(src, nxt + (w * RPW + i * 8) * 128);
            }
        }
        if (k < KN - 2) {
            #pragma unroll
            for (int i = 0; i < GLOADS; ++i) idxn[i] = nbp[i][k + 2];
        }

        __builtin_amdgcn_s_setprio(1);
        #pragma unroll
        for (int j0 = 0; j0 < 2; ++j0) {
            short8v a[MB], b[4];
            #pragma unroll
            for (int mb = 0; mb < MB; ++mb) {
                int r = w * RPW + mb * 16 + lr;
                int ch = (j0 * 4 + lhi) ^ chbase;
                a[mb] = *(const short8v*)(cur + r * 128 + ch * 16);
            }
            #pragma unroll
            for (int nb = 0; nb < 4; ++nb) {
                int c = nb * 16 + lr;
                int ch = (j0 * 4 + lhi) ^ chbase;
                b[nb] = *(const short8v*)(cur + GB + c * 128 + ch * 16);
            }
            #pragma unroll
            for (int mb = 0; mb < MB; ++mb)
                #pragma unroll
                for (int nb = 0; nb < 4; ++nb)
                    acc[mb][nb] = __builtin_amdgcn_mfma_f32_16x16x32_bf16(
                        a[mb], b[nb], acc[mb][nb], 0, 0, 0);
        }
        __builtin_amdgcn_s_setprio(0);
    }

    // ---- epilogue: +res, relu, pack 2 cols, store bf16 ----
    #pragma unroll
    for (int mb = 0; mb < MB; ++mb) {
        #pragma unroll
        for (int nb = 0; nb < 4; ++nb) {
            #pragma unroll
            for (int r = 0; r < 4; ++r) {
                int rg = row0 + w * RPW + mb * 16 + lhi * 4 + r;
                int c = nb * 16 + lr;
                float v = acc[mb][nb][r];
                if (res != nullptr) v += bf2f(res[(size_t)rg * 64 + c]);
                v = fmaxf(v, 0.0f);
                float o = __shfl_xor(v, 1);
                if (!(l & 1)) {
                    uint pk = (uint)f2bf(v) | ((uint)f2bf(o) << 16);
                    *(uint*)((char*)out + (size_t)rg * 128 + (c << 1)) = pk;
                }
            }
        }
    }
}

// ---------------------------------------------------------------------------
// MFMA head (unchanged from R1)
// ---------------------------------------------------------------------------
__global__ __launch_bounds__(256) void head_mfma_k(
    const ushort* __restrict__ G, const int* __restrict__ next_occ,
    const ushort* __restrict__ Wsmall,
    const float* __restrict__ b0a, const float* __restrict__ b1a,
    const float* __restrict__ b0b, const float* __restrict__ b1b,
    const int* __restrict__ n_points, float* __restrict__ outp)
{
    __shared__ __align__(16) char sm[32768 + 22528 + 640];
    char* sG = sm;
    char* sH = sm + 16384;
    char* sWs = sm + 32768;
    float* sBf = (float*)(sm + 32768 + 22528);

    const int t = threadIdx.x;
    const int w = t >> 6, l = t & 63;
    const int row0 = blockIdx.x * 128;
    const int lr = l & 15, lhi = l >> 4;

    #pragma unroll
    for (int i = 0; i < 4; ++i) {
        int rt = w * 32 + i * 8 + (l >> 3);
        int row = row0 + rt;
        gload_lds16((const char*)G + (size_t)row * 128 + (((l & 7) ^ (rt & 7)) << 4),
                    sG + (w * 32 + i * 8) * 128);
    }
    for (int i = w; i < 22; i += 4)
        gload_lds16((const char*)Wsmall + i * 1024 + l * 16, sWs + i * 1024);
    if (t < 64)                 sBf[t] = b0a[t];
    else if (t < 128)           sBf[t] = b1a[t - 64];
    else if (t < 144)           sBf[128 + (t - 128)] = b0b[t - 128];
    else if (t < 160)           sBf[144 + (t - 144)] = b1b[t - 144];
    __syncthreads();

    const int wr0 = w * 32;
    float bacc = 0.0f;

    // ======== stage 0 ========
    f32x4 acc[2][4];
    #pragma unroll
    for (int a = 0; a < 2; ++a)
        #pragma unroll
        for (int b = 0; b < 4; ++b) acc[a][b] = (f32x4)0.0f;
    #pragma unroll
    for (int j0 = 0; j0 < 2; ++j0) {
        short8v a[2], b[4];
        #pragma unroll
        for (int mb = 0; mb < 2; ++mb) {
            int r = wr0 + mb * 16 + lr;
            int ch = (j0 * 4 + lhi) ^ (r & 7);
            a[mb] = *(const short8v*)(sG + r * 128 + ch * 16);
        }
        #pragma unroll
        for (int nb = 0; nb < 4; ++nb) {
            int c = nb * 16 + lr;
            int ch = (j0 * 4 + lhi) ^ (c & 7);
            b[nb] = *(const short8v*)(sWs + c * 128 + ch * 16);   // W0aT
        }
        #pragma unroll
        for (int mb = 0; mb < 2; ++mb)
            #pragma unroll
            for (int nb = 0; nb < 4; ++nb)
                acc[mb][nb] = __builtin_amdgcn_mfma_f32_16x16x32_bf16(
                    a[mb], b[nb], acc[mb][nb], 0, 0, 0);
    }
    #pragma unroll
    for (int mb = 0; mb < 2; ++mb)
        #pragma unroll
        for (int nb = 0; nb < 4; ++nb) {
            float bias = sBf[nb * 16 + lr];
            #pragma unroll
            for (int r = 0; r < 4; ++r) {
                int row = wr0 + mb * 16 + lhi * 4 + r;
                int j = nb * 16 + lr;
                float v = fmaxf(acc[mb][nb][r] + bias, 0.0f);
                *(ushort*)(sH + row * 128 + (((j >> 3) ^ (row & 7)) << 4) + (j & 7) * 2) = f2bf(v);
            }
        }
    f32x4 lg[2];
    lg[0] = (f32x4)0.0f; lg[1] = (f32x4)0.0f;
    #pragma unroll
    for (int j0 = 0; j0 < 2; ++j0) {
        short8v a[2], b;
        #pragma unroll
        for (int mb = 0; mb < 2; ++mb) {
            int r = wr0 + mb * 16 + lr;
            int ch = (j0 * 4 + lhi) ^ (r & 7);
            a[mb] = *(const short8v*)(sH + r * 128 + ch * 16);
        }
        {
            int c = lr;
            int ch = (j0 * 4 + lhi) ^ (c & 7);
            b = *(const short8v*)(sWs + 16384 + c * 128 + ch * 16); // W0bT
        }
        #pragma unroll
        for (int mb = 0; mb < 2; ++mb)
            lg[mb] = __builtin_amdgcn_mfma_f32_16x16x32_bf16(a[mb], b, lg[mb], 0, 0, 0);
    }
    #pragma unroll
    for (int mb = 0; mb < 2; ++mb)
        #pragma unroll
        for (int r = 0; r < 4; ++r) {
            int row = row0 + wr0 + mb * 16 + lhi * 4 + r;
            int lower = next_occ[row] & 15;
            float lv = lg[mb][r] + sBf[128 + lr];
            float m = lv;
            #pragma unroll
            for (int s = 1; s < 16; s <<= 1) m = fmaxf(m, __shfl_xor(m, s));
            float e = __expf(lv - m), ss = e;
            #pragma unroll
            for (int s = 1; s < 16; s <<= 1) ss += __shfl_xor(ss, s);
            float lt = __shfl(lv, (l & 48) + lower);
            float p = __expf(lt - m) / ss;
            float bits = fminf(fmaxf(-log2f(p + 1e-10f), 0.0f), 50.0f);
            if (lr == 0) bacc += bits;
        }

    // ======== stage 1 ========
    f32x4 acc1[2][4];
    #pragma unroll
    for (int a = 0; a < 2; ++a)
        #pragma unroll
        for (int b = 0; b < 4; ++b) acc1[a][b] = (f32x4)0.0f;
    #pragma unroll
    for (int j0 = 0; j0 < 2; ++j0) {
        short8v a[2], b[4];
        #pragma unroll
        for (int mb = 0; mb < 2; ++mb) {
            int rloc = wr0 + mb * 16 + lr;
            int low = next_occ[row0 + rloc] & 15;
            int ch = (j0 * 4 + lhi) ^ (rloc & 7);
            short8v g8 = *(const short8v*)(sG + rloc * 128 + ch * 16);
            int che = (j0 * 4 + lhi) ^ (low & 7);
            short8v e8 = *(const short8v*)(sWs + 20480 + low * 128 + che * 16); // s1b
            #pragma unroll
            for (int e = 0; e < 8; ++e) {
                float f = bf2f((ushort)g8[e]) + bf2f((ushort)e8[e]);
                a[mb][e] = (short)f2bf(f);
            }
        }
        #pragma unroll
        for (int nb = 0; nb < 4; ++nb) {
            int c = nb * 16 + lr;
            int ch = (j0 * 4 + lhi) ^ (c & 7);
            b[nb] = *(const short8v*)(sWs + 8192 + c * 128 + ch * 16);  // W1aT
        }
        #pragma unroll
        for (int mb = 0; mb < 2; ++mb)
            #pragma unroll
            for (int nb = 0; nb < 4; ++nb)
                acc1[mb][nb] = __builtin_amdgcn_mfma_f32_16x16x32_bf16(
                    a[mb], b[nb], acc1[mb][nb], 0, 0, 0);
    }
    #pragma unroll
    for (int mb = 0; mb < 2; ++mb)
        #pragma unroll
        for (int nb = 0; nb < 4; ++nb) {
            float bias = sBf[64 + nb * 16 + lr];
            #pragma unroll
            for (int r = 0; r < 4; ++r) {
                int row = wr0 + mb * 16 + lhi * 4 + r;
                int j = nb * 16 + lr;
                float v = fmaxf(acc1[mb][nb][r] + bias, 0.0f);
                *(ushort*)(sH + row * 128 + (((j >> 3) ^ (row & 7)) << 4) + (j & 7) * 2) = f2bf(v);
            }
        }
    lg[0] = (f32x4)0.0f; lg[1] = (f32x4)0.0f;
    #pragma unroll
    for (int j0 = 0; j0 < 2; ++j0) {
        short8v a[2], b;
        #pragma unroll
        for (int mb = 0; mb < 2; ++mb) {
            int r = wr0 + mb * 16 + lr;
            int ch = (j0 * 4 + lhi) ^ (r & 7);
            a[mb] = *(const short8v*)(sH + r * 128 + ch * 16);
        }
        {
            int c = lr;
            int ch = (j0 * 4 + lhi) ^ (c & 7);
            b = *(const short8v*)(sWs + 18432 + c * 128 + ch * 16); // W1bT
        }
        #pragma unroll
        for (int mb = 0; mb < 2; ++mb)
            lg[mb] = __builtin_amdgcn_mfma_f32_16x16x32_bf16(a[mb], b, lg[mb], 0, 0, 0);
    }
    #pragma unroll
    for (int mb = 0; mb < 2; ++mb)
        #pragma unroll
        for (int r = 0; r < 4; ++r) {
            int row = row0 + wr0 + mb * 16 + lhi * 4 + r;
            int upper = next_occ[row] >> 4;
            float lv = lg[mb][r] + sBf[144 + lr];
            float m = lv;
            #pragma unroll
            for (int s = 1; s < 16; s <<= 1) m = fmaxf(m, __shfl_xor(m, s));
            float e = __expf(lv - m), ss = e;
            #pragma unroll
            for (int s = 1; s < 16; s <<= 1) ss += __shfl_xor(ss, s);
            float lt = __shfl(lv, (l & 48) + upper);
            float p = __expf(lt - m) / ss;
            float bits = fminf(fmaxf(-log2f(p + 1e-10f), 0.0f), 50.0f);
            if (lr == 0) bacc += bits;
        }

    bacc += __shfl_xor(bacc, 16);
    bacc += __shfl_xor(bacc, 32);
    if (l == 0) atomicAdd(outp, bacc / (float)(*n_points));
}

// ---------------------------------------------------------------------------
extern "C" void kernel_launch(void* const* d_in, const int* in_sizes, int n_in,
                              void* d_out, int out_size, void* d_ws, size_t ws_size,
                              hipStream_t stream)
{
    const float* prior_emb = (const float*)d_in[0];
    const float* temb8     = (const float*)d_in[1];
    const float* Wp        = (const float*)d_in[2];
    const float* Wt        = (const float*)d_in[3];
    const float* W0a       = (const float*)d_in[4];
    const float* b0a       = (const float*)d_in[5];
    const float* W0b       = (const float*)d_in[6];
    const float* b0b       = (const float*)d_in[7];
    const float* W1a       = (const float*)d_in[8];
    const float* b1a       = (const float*)d_in[9];
    const float* W1b       = (const float*)d_in[10];
    const float* b1b       = (const float*)d_in[11];
    const float* s1_emb    = (const float*)d_in[12];
    const int*   curr_occ  = (const int*)d_in[13];
    const int*   next_occ  = (const int*)d_in[14];
    const int*   next_oct  = (const int*)d_in[15];
    const int*   parent    = (const int*)d_in[16];
    const int*   nbr_curr  = (const int*)d_in[17];
    const int*   nbr_next  = (const int*)d_in[18];
    const int*   n_points  = (const int*)d_in[19];
    float* out = (float*)d_out;

    char* wsb = (char*)d_ws;
    ushort* zpage = (ushort*)wsb;
    size_t off = 256;
    ushort* WpT = (ushort*)(wsb + off); off += (size_t)135 * 4096 * 2;
    ushort* WtT = (ushort*)(wsb + off); off += (size_t)135 * 4096 * 2;
    ushort* Wsmall = (ushort*)(wsb + off);
    ushort* W0aT = Wsmall;
    ushort* W1aT = Wsmall + 4096;
    ushort* W0bT = Wsmall + 8192;
    ushort* W1bT = Wsmall + 9216;
    ushort* s1bT = Wsmall + 10240;
    off += 11264 * 2;
    off = (off + 255) & ~(size_t)255;
    ushort* fA = (ushort*)(wsb + off); off += (size_t)NP1 * 64 * 2;
    ushort* fB = (ushort*)(wsb + off); off += (size_t)NP1 * 64 * 2;
    ushort* fC = (ushort*)(wsb + off); off += (size_t)NP1 * 64 * 2;
    ushort* gA = (ushort*)(wsb + off); off += (size_t)NP2 * 64 * 2;
    ushort* gB = (ushort*)(wsb + off); off += (size_t)NP2 * 64 * 2;
    ushort* gC = (ushort*)(wsb + off); off += (size_t)NP2 * 64 * 2;

    hipMemsetAsync(d_out, 0, sizeof(float), stream);
    hipMemsetAsync(zpage, 0, 256, stream);

    prep_wT_k<<<(135 * 4096 + 255) / 256, 256, 0, stream>>>(Wp, WpT, 135);
    prep_wT_k<<<(135 * 4096 + 255) / 256, 256, 0, stream>>>(Wt, WtT, 135);
    prep_wT_k<<<16, 256, 0, stream>>>(W0a, W0aT, 1);
    prep_wT_k<<<16, 256, 0, stream>>>(W1a, W1aT, 1);
    prep_wbT_k<<<4, 256, 0, stream>>>(W0b, W0bT);
    prep_wbT_k<<<4, 256, 0, stream>>>(W1b, W1bT);
    prep_s1_k<<<4, 256, 0, stream>>>(s1_emb, s1bT);

    gather_curr_k<<<(NP1 * 32 + 255) / 256, 256, 0, stream>>>(prior_emb, curr_occ, fA);

    const size_t WT = (size_t)KN * 4096;
    // N1: 32-row / 2-wave blocks -> 625 blocks.  N2: 128-row / 4-wave -> 625.
    spconv_pipe_k<2,1><<<625, 128, 0, stream>>>(fA, nbr_curr, WpT + 0 * WT, nullptr, fB, zpage);
    spconv_pipe_k<2,1><<<625, 128, 0, stream>>>(fB, nbr_curr, WpT + 1 * WT, nullptr, fC, zpage);
    spconv_pipe_k<2,1><<<625, 128, 0, stream>>>(fC, nbr_curr, WpT + 2 * WT, fB,      fA, zpage);
    spconv_pipe_k<2,1><<<625, 128, 0, stream>>>(fA, nbr_curr, WpT + 3 * WT, nullptr, fC, zpage);
    spconv_pipe_k<2,1><<<625, 128, 0, stream>>>(fC, nbr_curr, WpT + 4 * WT, fA,      fB, zpage);

    gather_next_k<<<(NP2 * 32 + 255) / 256, 256, 0, stream>>>(fB, parent, next_oct, temb8, gA);

    spconv_pipe_k<4,2><<<625, 256, 0, stream>>>(gA, nbr_next, WtT + 0 * WT, nullptr, gB, zpage);
    spconv_pipe_k<4,2><<<625, 256, 0, stream>>>(gB, nbr_next, WtT + 1 * WT, nullptr, gC, zpage);
    spconv_pipe_k<4,2><<<625, 256, 0, stream>>>(gC, nbr_next, WtT + 2 * WT, gB,      gA, zpage);
    spconv_pipe_k<4,2><<<625, 256, 0, stream>>>(gA, nbr_next, WtT + 3 * WT, nullptr, gC, zpage);
    spconv_pipe_k<4,2><<<625, 256, 0, stream>>>(gC, nbr_next, WtT + 4 * WT, gA,      gB, zpage);

    head_mfma_k<<<625, 256, 0, stream>>>(gB, next_occ, Wsmall,
                                         b0a, b1a, b0b, b1b, n_points, out);
}